// Round 1
// baseline (292.793 us; speedup 1.0000x reference)
//
#include <hip/hip_runtime.h>
#include <float.h>
#include <math.h>

// ---------------------------------------------------------------------------
// DRR via Siddon ray casting.  Constants from the reference:
//   NX=NY=NZ=192, H=W=192, SDR=300, DELX=DELY=2, X0=Y0=0, SPACING=1, BAM=1,
//   B=2, N_SUB=H*W/2=18432.
// Pipeline (all on `stream`):
//   memsets  -> init out=0, ws reduction identities, mark[]=0
//   reduce   -> soft_min / min / max over volume (order-independent, exact)
//   scatter  -> mark[subsample_idx[n]] = 1
//   compact  -> detector-ordered (approximately) list of selected pixels
//   ray      -> 8 alpha-chunks per ray, one thread each; atomicAdd partials
// ---------------------------------------------------------------------------

#define NDIM   192
#define HW     (NDIM * NDIM)          // 36864
#define NSUB   (HW / 2)               // 18432
#define NBATCH 2
#define NCHUNK 8
#define NVOX   (NDIM * NDIM * NDIM)   // 7077888
#define SDRF   300.0f

// ws layout (bytes):
//   [0]  u32 enc_softmin   (atomicMin, sortable encoding, init 0xFFFFFFFF)
//   [4]  u32 enc_rmin      (atomicMin, init 0xFFFFFFFF)
//   [8]  u32 enc_rmax      (atomicMax, init 0x00000000)
//   [12] u32 counter       (init 0)
//   [16 .. 16+HW)            mark bytes
//   [16+HW .. 16+HW+4*NSUB)  compacted pixel list (int)
#define WS_MARK_OFF 16
#define WS_LIST_OFF (16 + HW)

// Sortable-uint encoding of float: monotone increasing, so uint min/max ==
// float min/max.  min identity = 0xFFFFFFFF, max identity = 0x00000000.
__device__ __forceinline__ unsigned int encf(float f) {
    unsigned int u = __float_as_uint(f);
    return (u & 0x80000000u) ? ~u : (u | 0x80000000u);
}
__device__ __forceinline__ float decf(unsigned int u) {
    return __uint_as_float((u & 0x80000000u) ? (u ^ 0x80000000u) : ~u);
}

// --------------------------- reduction kernel ------------------------------
// soft_min = min over (-800, 350];  rmin/rmax = min/max over v > -800.
// (BAM == 1.0 so the v > 350 branch is the identity.)
__global__ __launch_bounds__(256) void reduce_kernel(
    const float* __restrict__ vol, unsigned int* __restrict__ ws) {
    int tid    = blockIdx.x * blockDim.x + threadIdx.x;
    int stride = gridDim.x * blockDim.x;
    float smin = FLT_MAX, rmin = FLT_MAX, rmax = -FLT_MAX;
    const float4* v4 = (const float4*)vol;
    const int n4 = NVOX / 4;
    for (int i = tid; i < n4; i += stride) {
        float4 v = v4[i];
        float a[4] = {v.x, v.y, v.z, v.w};
#pragma unroll
        for (int k = 0; k < 4; ++k) {
            float x = a[k];
            if (x > -800.0f) {
                rmin = fminf(rmin, x);
                rmax = fmaxf(rmax, x);
                if (x <= 350.0f) smin = fminf(smin, x);
            }
        }
    }
    // wave(64) reduction
#pragma unroll
    for (int off = 32; off > 0; off >>= 1) {
        smin = fminf(smin, __shfl_down(smin, off));
        rmin = fminf(rmin, __shfl_down(rmin, off));
        rmax = fmaxf(rmax, __shfl_down(rmax, off));
    }
    if ((threadIdx.x & 63) == 0) {
        atomicMin(&ws[0], encf(smin));
        atomicMin(&ws[1], encf(rmin));
        atomicMax(&ws[2], encf(rmax));
    }
}

// --------------------------- mark + compact --------------------------------
__global__ __launch_bounds__(256) void scatter_mark(
    const int* __restrict__ idx, unsigned char* __restrict__ mark) {
    int n = blockIdx.x * blockDim.x + threadIdx.x;
    if (n < NSUB) mark[idx[n]] = 1;
}

// Wave-aggregated atomicAdd keeps lane order; list ends up approximately
// detector-row-ordered -> coherent gathers in the ray kernel.
__global__ __launch_bounds__(256) void compact_kernel(
    const unsigned char* __restrict__ mark, unsigned int* __restrict__ counter,
    int* __restrict__ list) {
    int p = blockIdx.x * blockDim.x + threadIdx.x;
    if (p < HW && mark[p]) {
        unsigned int pos = atomicAdd(counter, 1u);
        list[pos] = p;
    }
}

// --------------------------- axis iterator init ----------------------------
// Find the first plane index (walking in the direction of increasing alpha)
// whose alpha = (i - s)/d is STRICTLY greater than a_lo.  Index-based exact
// recomputation matches the reference's alpha values bit-for-bit given the
// same s, d.
__device__ __forceinline__ void init_axis(float s, float d, float a_lo,
                                          int& i, int& st, float& na) {
    if (d > 0.0f) {
        st = 1;
        float f = s + a_lo * d;                 // alpha_i > a_lo  <=>  i > f
        int ii = (int)floorf(f) + 1;
        ii = max(0, min(ii, NDIM + 1));
        while (ii <= NDIM && ((float)ii - s) / d <= a_lo) ++ii;
        while (ii > 0 && ((float)(ii - 1) - s) / d > a_lo) --ii;
        i  = ii;
        na = (ii <= NDIM) ? ((float)ii - s) / d : FLT_MAX;
    } else {
        st = -1;
        float f = s + a_lo * d;                 // alpha_i > a_lo  <=>  i < f
        int ii = (int)ceilf(f) - 1;
        ii = max(-1, min(ii, NDIM));
        while (ii >= 0 && ((float)ii - s) / d <= a_lo) --ii;
        while (ii < NDIM && ((float)(ii + 1) - s) / d > a_lo) ++ii;
        i  = ii;
        na = (ii >= 0) ? ((float)ii - s) / d : FLT_MAX;
    }
}

// --------------------------- ray kernel ------------------------------------
// Thread mapping: tid = c * (NBATCH*NSUB) + b * NSUB + n.  Lanes of a wave
// share (c, b) and process 64 consecutive list entries -> adjacent detector
// pixels -> spatially coherent voxel gathers.
__global__ __launch_bounds__(256) void ray_kernel(
    const float* __restrict__ vol, const float* __restrict__ rot,
    const float* __restrict__ trans, const unsigned int* __restrict__ wsc,
    const int* __restrict__ list, float* __restrict__ out) {
    int tid    = blockIdx.x * blockDim.x + threadIdx.x;
    int within = tid % (NBATCH * NSUB);
    int c      = tid / (NBATCH * NSUB);
    int b      = within / NSUB;
    int n      = within % NSUB;

    int p  = list[n];
    int pi = p / NDIM;       // detector row  -> gy
    int pj = p % NDIM;       // detector col  -> gx

    // density normalization constants
    float smin = decf(wsc[0]);
    float rmin = decf(wsc[1]);
    float rmax = decf(wsc[2]);
    float dmin = fminf(smin, rmin);
    float dmax = fmaxf(smin, rmax);
    float scale = 1.0f / (dmax - dmin);

    // rotation R = Rz(r0) @ Ry(r1) @ Rx(r2)
    float rz = rot[b * 3 + 0], ry = rot[b * 3 + 1], rx = rot[b * 3 + 2];
    float cz = cosf(rz), sz = sinf(rz);
    float cy = cosf(ry), sy = sinf(ry);
    float cx = cosf(rx), sx = sinf(rx);
    float R00 = cz * cy;
    float R01 = cz * sy * sx - sz * cx;
    float R02 = sz * sx + cz * sy * cx;
    float R10 = sz * cy;
    float R11 = cz * cx + sz * sy * sx;
    float R12 = sz * sy * cx - cz * sx;
    float R20 = -sy;
    float R21 = cy * sx;
    float R22 = cy * cx;
    float tx = trans[b * 3 + 0] + 96.0f;
    float ty = trans[b * 3 + 1] + 96.0f;
    float tz = trans[b * 3 + 2] + 96.0f;

    float srcx = R02 * SDRF + tx;
    float srcy = R12 * SDRF + ty;
    float srcz = R22 * SDRF + tz;
    float gx = ((float)pj - 95.5f) * 2.0f;
    float gy = ((float)pi - 95.5f) * 2.0f;
    float tgx = R00 * gx + R01 * gy + R02 * (-SDRF) + tx;
    float tgy = R10 * gx + R11 * gy + R12 * (-SDRF) + ty;
    float tgz = R20 * gx + R21 * gy + R22 * (-SDRF) + tz;

    float sdx = tgx - srcx, sdy = tgy - srcy, sdz = tgz - srcz;
    float dsx = (sdx == 0.0f) ? 1e-9f : sdx;
    float dsy = (sdy == 0.0f) ? 1e-9f : sdy;
    float dsz = (sdz == 0.0f) ? 1e-9f : sdz;

    float af0 = (0.0f - srcx) / dsx, al0 = (192.0f - srcx) / dsx;
    float af1 = (0.0f - srcy) / dsy, al1 = (192.0f - srcy) / dsy;
    float af2 = (0.0f - srcz) / dsz, al2 = (192.0f - srcz) / dsz;
    float amin = fmaxf(fmaxf(fminf(af0, al0), fminf(af1, al1)), fminf(af2, al2));
    amin = fmaxf(amin, 0.0f);
    float amax = fminf(fminf(fmaxf(af0, al0), fmaxf(af1, al1)), fmaxf(af2, al2));
    amax = fminf(amax, 1.0f);
    amax = fmaxf(amax, amin);
    float ray_len = sqrtf(sdx * sdx + sdy * sdy + sdz * sdz);

    // this thread's alpha sub-interval
    float span = amax - amin;
    float a_lo = amin + span * ((float)c / (float)NCHUNK);
    float a_hi = (c == NCHUNK - 1) ? amax
                                   : amin + span * ((float)(c + 1) / (float)NCHUNK);

    int i0, i1, i2, st0, st1, st2;
    float na0, na1, na2;
    init_axis(srcx, dsx, a_lo, i0, st0, na0);
    init_axis(srcy, dsy, a_lo, i1, st1, na1);
    init_axis(srcz, dsz, a_lo, i2, st2, na2);

    float cur = a_lo;
    float acc = 0.0f;
    while (true) {
        float an  = fminf(fminf(na0, na1), na2);
        bool fin  = !(an < a_hi);
        float a2  = fin ? a_hi : an;
        float mid = 0.5f * (cur + a2);
        float px = srcx + mid * sdx;
        float py = srcy + mid * sdy;
        float pz = srcz + mid * sdz;
        int ix = min(max((int)floorf(px), 0), NDIM - 1);
        int iy = min(max((int)floorf(py), 0), NDIM - 1);
        int iz = min(max((int)floorf(pz), 0), NDIM - 1);
        // density = flip(volume, axis 0), then transform + normalize
        float v  = vol[((NDIM - 1 - ix) * NDIM + iy) * NDIM + iz];
        float dv = (v <= -800.0f) ? smin : v;
        acc += (a2 - cur) * ((dv - dmin) * scale);
        if (fin) break;
        cur = a2;
        // advance the axis that produced `an` (ties -> zero-length segment
        // next iteration; harmless).  Single division per step, branchless.
        bool c0 = (an == na0);
        bool c1 = !c0 && (an == na1);
        bool c2 = !c0 && !c1;
        int   inew = c0 ? (i0 + st0) : (c1 ? (i1 + st1) : (i2 + st2));
        float ssel = c0 ? srcx : (c1 ? srcy : srcz);
        float dsel = c0 ? dsx : (c1 ? dsy : dsz);
        float nan_ = ((unsigned)inew <= (unsigned)NDIM)
                         ? ((float)inew - ssel) / dsel
                         : FLT_MAX;
        if (c0) { i0 = inew; na0 = nan_; }
        if (c1) { i1 = inew; na1 = nan_; }
        if (c2) { i2 = inew; na2 = nan_; }
    }
    atomicAdd(&out[b * HW + p], acc * ray_len);
}

// --------------------------- launch ----------------------------------------
extern "C" void kernel_launch(void* const* d_in, const int* in_sizes, int n_in,
                              void* d_out, int out_size, void* d_ws,
                              size_t ws_size, hipStream_t stream) {
    const float* vol   = (const float*)d_in[0];
    const float* rot   = (const float*)d_in[1];
    const float* trans = (const float*)d_in[2];
    const int*   sidx  = (const int*)d_in[3];
    float* out = (float*)d_out;

    unsigned int*  wsu  = (unsigned int*)d_ws;
    unsigned char* mark = (unsigned char*)d_ws + WS_MARK_OFF;
    int*           list = (int*)((unsigned char*)d_ws + WS_LIST_OFF);

    // init: out = 0; enc_softmin/enc_rmin = 0xFFFFFFFF; enc_rmax = 0,
    // counter = 0, mark[] = 0
    hipMemsetAsync(d_out, 0, (size_t)out_size * sizeof(float), stream);
    hipMemsetAsync(wsu, 0xFF, 8, stream);
    hipMemsetAsync((unsigned char*)d_ws + 8, 0, 8 + HW, stream);

    reduce_kernel<<<1024, 256, 0, stream>>>(vol, wsu);
    scatter_mark<<<NSUB / 256, 256, 0, stream>>>(sidx, mark);
    compact_kernel<<<HW / 256, 256, 0, stream>>>(mark, &wsu[3], list);
    ray_kernel<<<(NBATCH * NSUB * NCHUNK) / 256, 256, 0, stream>>>(
        vol, rot, trans, wsu, list, out);
}

// Round 2
// 172.571 us; speedup vs baseline: 1.6966x; 1.6966x over previous
//
#include <hip/hip_runtime.h>
#include <float.h>
#include <math.h>

// ---------------------------------------------------------------------------
// DRR via Siddon ray casting.  Constants from the reference:
//   NX=NY=NZ=192, H=W=192, SDR=300, DELX=DELY=2, X0=Y0=0, SPACING=1, BAM=1,
//   B=2, N_SUB=H*W/2=18432.
// Pipeline (all on `stream`):
//   memsets  -> out=0, reduction identities, mark[]=0
//   reduce   -> soft_min / min / max over volume (branchless, 8 loads in
//               flight per thread, LDS block reduction, 3 atomics/block)
//   scatter  -> mark[subsample_idx[n]] = 1
//   ray      -> FULL detector, wave = 8x8 detector tile (coherent gather
//               front), 8 alpha-chunks per ray; masked atomicAdd at the end.
// ---------------------------------------------------------------------------

#define NDIM   192
#define HW     (NDIM * NDIM)          // 36864
#define NSUB   (HW / 2)               // 18432
#define NBATCH 2
#define NCHUNK 8
#define NVOX   (NDIM * NDIM * NDIM)   // 7077888
#define SDRF   300.0f
#define RB     864                    // reduce blocks: 864*256*8 f4 == NVOX/4

// ws layout (bytes):
//   [0]  u32 enc_softmin   (atomicMin, sortable encoding, init 0xFFFFFFFF)
//   [4]  u32 enc_rmin      (atomicMin, init 0xFFFFFFFF)
//   [8]  u32 enc_rmax      (atomicMax, init 0x00000000)
//   [12] pad
//   [16 .. 16+HW)  mark bytes
#define WS_MARK_OFF 16

// Sortable-uint encoding of float: monotone increasing, so uint min/max ==
// float min/max.  min identity = 0xFFFFFFFF, max identity = 0x00000000.
__device__ __forceinline__ unsigned int encf(float f) {
    unsigned int u = __float_as_uint(f);
    return (u & 0x80000000u) ? ~u : (u | 0x80000000u);
}
__device__ __forceinline__ float decf(unsigned int u) {
    return __uint_as_float((u & 0x80000000u) ? (u ^ 0x80000000u) : ~u);
}

// --------------------------- reduction kernel ------------------------------
// soft_min = min over (-800, 350];  rmin/rmax = min/max over v > -800.
// (BAM == 1.0 so the v > 350 branch is the identity.)
// Branchless; 8 independent float4 loads issued back-to-back per thread.
__global__ void reduce_kernel(const float* __restrict__ vol,
                              unsigned int* __restrict__ ws) {
    const int tid = blockIdx.x * 256 + threadIdx.x;
    const float4* __restrict__ v4 = (const float4*)vol;

    float4 r0 = v4[tid + 0 * (RB * 256)];
    float4 r1 = v4[tid + 1 * (RB * 256)];
    float4 r2 = v4[tid + 2 * (RB * 256)];
    float4 r3 = v4[tid + 3 * (RB * 256)];
    float4 r4 = v4[tid + 4 * (RB * 256)];
    float4 r5 = v4[tid + 5 * (RB * 256)];
    float4 r6 = v4[tid + 6 * (RB * 256)];
    float4 r7 = v4[tid + 7 * (RB * 256)];

    float smin = FLT_MAX, rmin = FLT_MAX, rmax = -FLT_MAX;
    float4 rr[8] = {r0, r1, r2, r3, r4, r5, r6, r7};
#pragma unroll
    for (int k = 0; k < 8; ++k) {
        float xs[4] = {rr[k].x, rr[k].y, rr[k].z, rr[k].w};
#pragma unroll
        for (int j = 0; j < 4; ++j) {
            float x = xs[j];
            bool in = (x > -800.0f);
            rmin = fminf(rmin, in ? x : FLT_MAX);
            rmax = fmaxf(rmax, in ? x : -FLT_MAX);
            smin = fminf(smin, (in && x <= 350.0f) ? x : FLT_MAX);
        }
    }
    // wave(64) butterfly
#pragma unroll
    for (int off = 32; off > 0; off >>= 1) {
        smin = fminf(smin, __shfl_down(smin, off));
        rmin = fminf(rmin, __shfl_down(rmin, off));
        rmax = fmaxf(rmax, __shfl_down(rmax, off));
    }
    __shared__ float sm[4], rm[4], rx[4];
    int w = threadIdx.x >> 6;
    if ((threadIdx.x & 63) == 0) { sm[w] = smin; rm[w] = rmin; rx[w] = rmax; }
    __syncthreads();
    if (threadIdx.x == 0) {
        float a = fminf(fminf(sm[0], sm[1]), fminf(sm[2], sm[3]));
        float b = fminf(fminf(rm[0], rm[1]), fminf(rm[2], rm[3]));
        float c = fmaxf(fmaxf(rx[0], rx[1]), fmaxf(rx[2], rx[3]));
        atomicMin(&ws[0], encf(a));
        atomicMin(&ws[1], encf(b));
        atomicMax(&ws[2], encf(c));
    }
}

// --------------------------- mark ------------------------------------------
__global__ __launch_bounds__(256) void scatter_mark(
    const int* __restrict__ idx, unsigned char* __restrict__ mark) {
    int n = blockIdx.x * blockDim.x + threadIdx.x;
    if (n < NSUB) mark[idx[n]] = 1;
}

// --------------------------- axis iterator init ----------------------------
// First plane index (walking toward increasing alpha) whose
// alpha = (i - s)/d is STRICTLY greater than a_lo.
__device__ __forceinline__ void init_axis(float s, float d, float a_lo,
                                          int& i, int& st, float& na) {
    if (d > 0.0f) {
        st = 1;
        float f = s + a_lo * d;
        int ii = (int)floorf(f) + 1;
        ii = max(0, min(ii, NDIM + 1));
        while (ii <= NDIM && ((float)ii - s) / d <= a_lo) ++ii;
        while (ii > 0 && ((float)(ii - 1) - s) / d > a_lo) --ii;
        i  = ii;
        na = (ii <= NDIM) ? ((float)ii - s) / d : FLT_MAX;
    } else {
        st = -1;
        float f = s + a_lo * d;
        int ii = (int)ceilf(f) - 1;
        ii = max(-1, min(ii, NDIM));
        while (ii >= 0 && ((float)ii - s) / d <= a_lo) --ii;
        while (ii < NDIM && ((float)(ii + 1) - s) / d > a_lo) ++ii;
        i  = ii;
        na = (ii >= 0) ? ((float)ii - s) / d : FLT_MAX;
    }
}

// --------------------------- ray kernel ------------------------------------
// Full detector.  Block = 256 threads = 4 waves; wave = one 8x8 detector
// tile (lane -> pixel-in-tile), so each step's 64-lane gather front is a
// compact 3D patch -> few cache-line transactions.  Grid.y = alpha chunk,
// grid.z = batch.  Unselected pixels are computed but not written.
__global__ __launch_bounds__(256) void ray_kernel(
    const float* __restrict__ vol, const float* __restrict__ rot,
    const float* __restrict__ trans, const unsigned int* __restrict__ wsc,
    const unsigned char* __restrict__ mark, float* __restrict__ out) {
    const int lane = threadIdx.x & 63;
    const int tile = blockIdx.x * 4 + (threadIdx.x >> 6);   // 0..575
    const int pi = (tile / 24) * 8 + (lane >> 3);
    const int pj = (tile % 24) * 8 + (lane & 7);
    const int p  = pi * NDIM + pj;
    const int c  = blockIdx.y;
    const int b  = blockIdx.z;

    // density normalization constants
    float smin = decf(wsc[0]);
    float rmin = decf(wsc[1]);
    float rmax = decf(wsc[2]);
    float dmin = fminf(smin, rmin);
    float dmax = fmaxf(smin, rmax);
    float scale = 1.0f / (dmax - dmin);

    // rotation R = Rz(r0) @ Ry(r1) @ Rx(r2)
    float rz = rot[b * 3 + 0], ry = rot[b * 3 + 1], rx = rot[b * 3 + 2];
    float cz = cosf(rz), sz = sinf(rz);
    float cy = cosf(ry), sy = sinf(ry);
    float cx = cosf(rx), sx = sinf(rx);
    float R00 = cz * cy;
    float R01 = cz * sy * sx - sz * cx;
    float R02 = sz * sx + cz * sy * cx;
    float R10 = sz * cy;
    float R11 = cz * cx + sz * sy * sx;
    float R12 = sz * sy * cx - cz * sx;
    float R20 = -sy;
    float R21 = cy * sx;
    float R22 = cy * cx;
    float tx = trans[b * 3 + 0] + 96.0f;
    float ty = trans[b * 3 + 1] + 96.0f;
    float tz = trans[b * 3 + 2] + 96.0f;

    float srcx = R02 * SDRF + tx;
    float srcy = R12 * SDRF + ty;
    float srcz = R22 * SDRF + tz;
    float gx = ((float)pj - 95.5f) * 2.0f;
    float gy = ((float)pi - 95.5f) * 2.0f;
    float tgx = R00 * gx + R01 * gy + R02 * (-SDRF) + tx;
    float tgy = R10 * gx + R11 * gy + R12 * (-SDRF) + ty;
    float tgz = R20 * gx + R21 * gy + R22 * (-SDRF) + tz;

    float sdx = tgx - srcx, sdy = tgy - srcy, sdz = tgz - srcz;
    float dsx = (sdx == 0.0f) ? 1e-9f : sdx;
    float dsy = (sdy == 0.0f) ? 1e-9f : sdy;
    float dsz = (sdz == 0.0f) ? 1e-9f : sdz;

    float af0 = (0.0f - srcx) / dsx, al0 = (192.0f - srcx) / dsx;
    float af1 = (0.0f - srcy) / dsy, al1 = (192.0f - srcy) / dsy;
    float af2 = (0.0f - srcz) / dsz, al2 = (192.0f - srcz) / dsz;
    float amin = fmaxf(fmaxf(fminf(af0, al0), fminf(af1, al1)), fminf(af2, al2));
    amin = fmaxf(amin, 0.0f);
    float amax = fminf(fminf(fmaxf(af0, al0), fmaxf(af1, al1)), fmaxf(af2, al2));
    amax = fminf(amax, 1.0f);
    amax = fmaxf(amax, amin);
    float ray_len = sqrtf(sdx * sdx + sdy * sdy + sdz * sdz);

    // this thread's alpha sub-interval
    float span = amax - amin;
    float a_lo = amin + span * ((float)c / (float)NCHUNK);
    float a_hi = (c == NCHUNK - 1) ? amax
                                   : amin + span * ((float)(c + 1) / (float)NCHUNK);

    int i0, i1, i2, st0, st1, st2;
    float na0, na1, na2;
    init_axis(srcx, dsx, a_lo, i0, st0, na0);
    init_axis(srcy, dsy, a_lo, i1, st1, na1);
    init_axis(srcz, dsz, a_lo, i2, st2, na2);

    float cur = a_lo;
    float acc = 0.0f;
    while (true) {
        float an  = fminf(fminf(na0, na1), na2);
        bool fin  = !(an < a_hi);
        float a2  = fin ? a_hi : an;
        float mid = 0.5f * (cur + a2);
        float px = srcx + mid * sdx;
        float py = srcy + mid * sdy;
        float pz = srcz + mid * sdz;
        int ix = min(max((int)floorf(px), 0), NDIM - 1);
        int iy = min(max((int)floorf(py), 0), NDIM - 1);
        int iz = min(max((int)floorf(pz), 0), NDIM - 1);
        // density = flip(volume, axis 0), then transform + normalize
        float v  = vol[((NDIM - 1 - ix) * NDIM + iy) * NDIM + iz];
        float dv = (v <= -800.0f) ? smin : v;
        acc += (a2 - cur) * ((dv - dmin) * scale);
        if (fin) break;
        cur = a2;
        bool c0 = (an == na0);
        bool c1 = !c0 && (an == na1);
        bool c2 = !c0 && !c1;
        int   inew = c0 ? (i0 + st0) : (c1 ? (i1 + st1) : (i2 + st2));
        float ssel = c0 ? srcx : (c1 ? srcy : srcz);
        float dsel = c0 ? dsx : (c1 ? dsy : dsz);
        float nan_ = ((unsigned)inew <= (unsigned)NDIM)
                         ? ((float)inew - ssel) / dsel
                         : FLT_MAX;
        if (c0) { i0 = inew; na0 = nan_; }
        if (c1) { i1 = inew; na1 = nan_; }
        if (c2) { i2 = inew; na2 = nan_; }
    }
    if (mark[p]) atomicAdd(&out[b * HW + p], acc * ray_len);
}

// --------------------------- launch ----------------------------------------
extern "C" void kernel_launch(void* const* d_in, const int* in_sizes, int n_in,
                              void* d_out, int out_size, void* d_ws,
                              size_t ws_size, hipStream_t stream) {
    const float* vol   = (const float*)d_in[0];
    const float* rot   = (const float*)d_in[1];
    const float* trans = (const float*)d_in[2];
    const int*   sidx  = (const int*)d_in[3];
    float* out = (float*)d_out;

    unsigned int*  wsu  = (unsigned int*)d_ws;
    unsigned char* mark = (unsigned char*)d_ws + WS_MARK_OFF;

    hipMemsetAsync(d_out, 0, (size_t)out_size * sizeof(float), stream);
    hipMemsetAsync(wsu, 0xFF, 8, stream);             // enc_softmin, enc_rmin
    hipMemsetAsync((unsigned char*)d_ws + 8, 0, 8 + HW, stream);  // rmax, mark

    reduce_kernel<<<RB, 256, 0, stream>>>(vol, wsu);
    scatter_mark<<<NSUB / 256, 256, 0, stream>>>(sidx, mark);
    dim3 rgrid(576 / 4, NCHUNK, NBATCH);
    ray_kernel<<<rgrid, 256, 0, stream>>>(vol, rot, trans, wsu, mark, out);
}